// Round 10
// baseline (203.626 us; speedup 1.0000x reference)
//
#include <hip/hip_runtime.h>
#include <stdint.h>

typedef unsigned short ushort_t;
typedef __bf16 bf16x8 __attribute__((ext_vector_type(8)));
typedef float floatx4 __attribute__((ext_vector_type(4)));
typedef float floatx16 __attribute__((ext_vector_type(16)));
typedef unsigned int uintx4 __attribute__((ext_vector_type(4)));

#define B_   8
#define S_   1024
#define D_   768
#define H_   12
#define M_   (B_ * S_)   // 8192
#define N3_  (3 * D_)    // 2304
#define QK_  1536        // qk buffer row stride (Q at +0, K at +768)
#define QSCALE 0.18033688f   // 0.125 * log2(e): folded into Q at GEMM epilogue

static __device__ __forceinline__ void gl_lds16(const void* g, void* l) {
  __builtin_amdgcn_global_load_lds((const __attribute__((address_space(1))) void*)g,
                                   (__attribute__((address_space(3))) void*)l,
                                   16, 0, 0);
}

static __device__ __forceinline__ ushort_t f2bf(float f) {
  __bf16 h = (__bf16)f;
  return __builtin_bit_cast(unsigned short, h);
}

static __device__ __forceinline__ void store_out(ushort_t* p, float v) { *p = f2bf(v); }
static __device__ __forceinline__ void store_out(float* p, float v) { *p = v; }

// pack two f32 -> one u32 of two bf16 (lo, hi). T12 recipe: no builtin.
static __device__ __forceinline__ unsigned cvt_pk_bf16(float lo, float hi) {
  unsigned d;
  asm("v_cvt_pk_bf16_f32 %0, %1, %2" : "=v"(d) : "v"(lo), "v"(hi));
  return d;
}
// v_permlane32_swap_b32 a, b: a.hi-lanes <- b.lo-lanes ; b.lo-lanes <- a.hi-lanes
static __device__ __forceinline__ void plane32_swap(unsigned& a, unsigned& b) {
  asm volatile("v_permlane32_swap_b32 %0, %1" : "+v"(a), "+v"(b));
}

// ---------------------------------------------------------------------------
// Merged prep (r8/r9-verified): x f32->bf16 vectorized x4, w transposes.
// ---------------------------------------------------------------------------
static __device__ __forceinline__ void transpose_tile(const float* __restrict__ W,
                                                      ushort_t* __restrict__ Wt,
                                                      int K, int N, int bx, int by,
                                                      int t) {
  __shared__ float tile[32][33];
  const int n0 = bx * 32, k0 = by * 32;
  const int tx = t & 31, ty = t >> 5;
#pragma unroll
  for (int i = 0; i < 4; ++i)
    tile[ty + i * 8][tx] = W[(size_t)(k0 + ty + i * 8) * N + n0 + tx];
  __syncthreads();
#pragma unroll
  for (int i = 0; i < 4; ++i)
    Wt[(size_t)(n0 + ty + i * 8) * K + k0 + tx] = f2bf(tile[tx][ty + i * 8]);
}

__global__ __launch_bounds__(256) void prep_kernel(const float* __restrict__ x,
                                                   ushort_t* __restrict__ xb,
                                                   const float* __restrict__ w_qkv,
                                                   ushort_t* __restrict__ wqkvt,
                                                   const float* __restrict__ w_proj,
                                                   ushort_t* __restrict__ wprojt) {
  const int gb = blockIdx.x, t = threadIdx.x;
  if (gb < 6144) {
    const int i = (gb * 256 + t) * 4;
    const float4 v = *(const float4*)(x + i);
    ushort4 o4;
    o4.x = f2bf(v.x); o4.y = f2bf(v.y); o4.z = f2bf(v.z); o4.w = f2bf(v.w);
    *(ushort4*)(xb + i) = o4;
  } else if (gb < 6144 + 1728) {
    const int lb = gb - 6144;                  // 72 x 24 tiles
    transpose_tile(w_qkv, wqkvt, D_, N3_, lb % 72, lb / 72, t);
  } else {
    const int lb = gb - 6144 - 1728;           // 24 x 24 tiles
    transpose_tile(w_proj, wprojt, D_, D_, lb % 24, lb / 24, t);
  }
}

// ---------------------------------------------------------------------------
// QKV GEMM v10: BM=256 x BN=128, 512 threads (8 waves, 4Mx2N), r0's proven
// 2-barrier single-buffer loop. Per-WAVE work is byte-identical to the 128^2
// kernel (64x64 out, 8 ds_read_b128 + 16 MFMA per K-step, same conflict-free
// swizzle, same epilogue math). The block envelope doubles:
//   - grid 1152 -> 576 blocks: total staged bytes 453 -> 340 MB (-25%)
//   - total latency-exposed barrier events 27648 -> 13824 (-50%)
//   - launch_bounds(512,4): ~100 VGPR (r9 measured 80 for this wave body)
//     -> 2 blocks/CU, 16 waves/CU resident (vs ~7 measured at 128^2)
//   - 576 = 8 x 72 -> bijective XCD swizzle; V boundary 1536 = 12*128 stays
//     block-aligned; m0 is 256-aligned so a block never straddles a batch.
// ---------------------------------------------------------------------------
template <typename OutT, bool SPLITV>
__global__ __launch_bounds__(512, 4) void gemm_bm256(const ushort_t* __restrict__ A,
                                                     const ushort_t* __restrict__ Bt,
                                                     const float* __restrict__ bias,
                                                     OutT* __restrict__ C, int CN,
                                                     ushort_t* __restrict__ vt,
                                                     int NBX, int CHUNK) {
  __shared__ __align__(16) ushort_t As[256 * 32];   // 16 KB
  __shared__ __align__(16) ushort_t Bs[128 * 32];   //  8 KB
  const int t = threadIdx.x;
  const int wave = t >> 6, lane = t & 63;
  const int quad = lane >> 4, l15 = lane & 15;
  const int wm = wave >> 1, wn = wave & 1;          // 4 x 2 wave grid

  // XCD-aware bijective swizzle (grid % 8 == 0)
  const int g = blockIdx.x;
  const int swz = (g & 7) * CHUNK + (g >> 3);
  const int bx = swz % NBX, by = swz / NBX;
  const int m0 = by * 256, n0 = bx * 128;

  const int scol  = ((lane & 3) ^ ((lane >> 3) & 3)) * 8;  // source granule
  const int slotq = (quad ^ ((l15 >> 1) & 3)) * 8;         // frag read slot

  floatx4 acc[4][4];
#pragma unroll
  for (int i = 0; i < 4; ++i)
#pragma unroll
    for (int j = 0; j < 4; ++j) acc[i][j] = (floatx4)0.0f;

  for (int k0 = 0; k0 < 768; k0 += 32) {
    if (k0) __syncthreads();
    // stage A: 1024 granules (2/thread); row = (c*512 + wave*64 + lane)>>2
#pragma unroll
    for (int c = 0; c < 2; ++c) {
      const int i0 = c * 512 + wave * 64;  // wave-uniform LDS base
      const int row = (i0 + lane) >> 2;
      gl_lds16(A + (size_t)(m0 + row) * 768 + k0 + scol, As + i0 * 8);
    }
    // stage B: 512 granules (1/thread); row = t>>2
    {
      const int i0 = wave * 64;
      const int row = (i0 + lane) >> 2;
      gl_lds16(Bt + (size_t)(n0 + row) * 768 + k0 + scol, Bs + i0 * 8);
    }
    __syncthreads();

    bf16x8 af[4], bfr[4];
#pragma unroll
    for (int mi = 0; mi < 4; ++mi)
      af[mi] = *(const bf16x8*)(As + (wm * 64 + mi * 16 + l15) * 32 + slotq);
#pragma unroll
    for (int ni = 0; ni < 4; ++ni)
      bfr[ni] = *(const bf16x8*)(Bs + (wn * 64 + ni * 16 + l15) * 32 + slotq);
#pragma unroll
    for (int mi = 0; mi < 4; ++mi)
#pragma unroll
      for (int ni = 0; ni < 4; ++ni)
        acc[mi][ni] = __builtin_amdgcn_mfma_f32_16x16x32_bf16(af[mi], bfr[ni], acc[mi][ni], 0, 0, 0);
  }

#pragma unroll
  for (int ni = 0; ni < 4; ++ni) {
    const int colb = n0 + wn * 64 + ni * 16;   // wave-uniform
    const int col = colb + l15;
    const float bb = bias[col];
    if (SPLITV && colb >= 1536) {
      const int hh = (colb - 1536) >> 6;
      const int d  = ((colb - 1536) & 63) + l15;
      const int bh = (m0 >> 10) * H_ + hh;
      ushort_t* vrow = vt + ((size_t)bh * 64 + d) * 1024 +
                       (m0 & 1023) + wm * 64 + quad * 4;
#pragma unroll
      for (int mi = 0; mi < 4; ++mi) {
        ushort4 pk;
        pk.x = f2bf(acc[mi][ni][0] + bb);
        pk.y = f2bf(acc[mi][ni][1] + bb);
        pk.z = f2bf(acc[mi][ni][2] + bb);
        pk.w = f2bf(acc[mi][ni][3] + bb);
        *(ushort4*)(vrow + mi * 16) = pk;
      }
    } else {
      const float sc = (SPLITV && colb < 768) ? QSCALE : 1.0f;
#pragma unroll
      for (int mi = 0; mi < 4; ++mi) {
#pragma unroll
        for (int r = 0; r < 4; ++r) {
          const int row = m0 + wm * 64 + mi * 16 + quad * 4 + r;
          store_out(&C[(size_t)row * CN + col], (acc[mi][ni][r] + bb) * sc);
        }
      }
    }
  }
}

// ---------------------------------------------------------------------------
// proj GEMM (r9-verified verbatim 128^2 structure).
// ---------------------------------------------------------------------------
template <typename OutT, bool SPLITV>
__global__ __launch_bounds__(256) void gemm_bt_bias(const ushort_t* __restrict__ A,
                                                    const ushort_t* __restrict__ Bt,
                                                    const float* __restrict__ bias,
                                                    OutT* __restrict__ C, int CN,
                                                    ushort_t* __restrict__ vt) {
  __shared__ __align__(16) ushort_t As[128 * 32];
  __shared__ __align__(16) ushort_t Bs[128 * 32];
  const int t = threadIdx.x;
  const int wave = t >> 6, lane = t & 63;
  const int quad = lane >> 4, l15 = lane & 15;
  const int wm = wave >> 1, wn = wave & 1;
  const int m0 = blockIdx.y * 128, n0 = blockIdx.x * 128;

  const int scol  = ((lane & 3) ^ ((lane >> 3) & 3)) * 8;  // source granule
  const int slotq = (quad ^ ((l15 >> 1) & 3)) * 8;         // frag read slot

  floatx4 acc[4][4];
#pragma unroll
  for (int i = 0; i < 4; ++i)
#pragma unroll
    for (int j = 0; j < 4; ++j) acc[i][j] = (floatx4)0.0f;

  for (int k0 = 0; k0 < 768; k0 += 32) {
    if (k0) __syncthreads();
#pragma unroll
    for (int c = 0; c < 2; ++c) {
      const int i0 = c * 256 + wave * 64;  // wave-uniform LDS base
      const int i = i0 + lane;
      const int row = i >> 2;
      gl_lds16(A + (size_t)(m0 + row) * 768 + k0 + scol, As + i0 * 8);
      gl_lds16(Bt + (size_t)(n0 + row) * 768 + k0 + scol, Bs + i0 * 8);
    }
    __syncthreads();

    bf16x8 af[4], bfr[4];
#pragma unroll
    for (int mi = 0; mi < 4; ++mi)
      af[mi] = *(const bf16x8*)(As + (wm * 64 + mi * 16 + l15) * 32 + slotq);
#pragma unroll
    for (int ni = 0; ni < 4; ++ni)
      bfr[ni] = *(const bf16x8*)(Bs + (wn * 64 + ni * 16 + l15) * 32 + slotq);
#pragma unroll
    for (int mi = 0; mi < 4; ++mi)
#pragma unroll
      for (int ni = 0; ni < 4; ++ni)
        acc[mi][ni] = __builtin_amdgcn_mfma_f32_16x16x32_bf16(af[mi], bfr[ni], acc[mi][ni], 0, 0, 0);
  }

#pragma unroll
  for (int ni = 0; ni < 4; ++ni) {
    const int colb = n0 + wn * 64 + ni * 16;   // wave-uniform
    const int col = colb + l15;
    const float bb = bias[col];
    if (SPLITV && colb >= 1536) {
      const int hh = (colb - 1536) >> 6;
      const int d  = ((colb - 1536) & 63) + l15;
      const int bh = (m0 >> 10) * H_ + hh;
      ushort_t* vrow = vt + ((size_t)bh * 64 + d) * 1024 +
                       (m0 & 1023) + wm * 64 + quad * 4;
#pragma unroll
      for (int mi = 0; mi < 4; ++mi) {
        ushort4 pk;
        pk.x = f2bf(acc[mi][ni][0] + bb);
        pk.y = f2bf(acc[mi][ni][1] + bb);
        pk.z = f2bf(acc[mi][ni][2] + bb);
        pk.w = f2bf(acc[mi][ni][3] + bb);
        *(ushort4*)(vrow + mi * 16) = pk;
      }
    } else {
      const float sc = (SPLITV && colb < 768) ? QSCALE : 1.0f;
#pragma unroll
      for (int mi = 0; mi < 4; ++mi) {
#pragma unroll
        for (int r = 0; r < 4; ++r) {
          const int row = m0 + wm * 64 + mi * 16 + quad * 4 + r;
          store_out(&C[(size_t)row * CN + col], (acc[mi][ni][r] + bb) * sc);
        }
      }
    }
  }
}

// ---------------------------------------------------------------------------
// Flash attention v7 (r9-verified verbatim): 32x32x16 MFMA + swapped QK^T +
// in-register softmax (cvt_pk_bf16 + permlane32_swap), QBLK 128, grid 768.
// ---------------------------------------------------------------------------
__global__ __launch_bounds__(256, 3) void attn_kernel(const ushort_t* __restrict__ qk,
                                                      const ushort_t* __restrict__ vt,
                                                      ushort_t* __restrict__ o) {
  __shared__ __align__(16) ushort_t Qs[128 * 64];   // 16 KB
  __shared__ __align__(16) ushort_t Ks[64 * 64];    //  8 KB
  __shared__ __align__(16) ushort_t Vts[64 * 64];   //  8 KB (V^T, swizzled)
  __shared__ float Ls[128];                         // 512 B

  const int t = threadIdx.x;
  const int wave = t >> 6, lane = t & 63;
  const int l31 = lane & 31, hi = lane >> 5, l7 = lane & 7;

  // XCD swizzle: 768 blocks; xcd=g&7 gets 12 contiguous bh, 8 q-tiles each.
  const int g = blockIdx.x;
  const int xcd = g & 7, gi = g >> 3;          // gi in 0..95
  const int bh = xcd * 12 + (gi >> 3);         // 0..95
  const int q0 = (gi & 7) * 128;
  const int h = bh % H_;
  const int bS = (bh / H_) * S_;
  const ushort_t* vbase = vt + (size_t)bh * 64 * 1024;

  // prologue: stage Q (1024 granules) + K/V tile 0, swizzled source
#pragma unroll
  for (int c = 0; c < 4; ++c) {
    const int i0 = c * 256 + wave * 64;  // wave-uniform
    const int i = i0 + lane;
    const int row = i >> 3, sg = (i & 7) ^ (row & 7);
    gl_lds16(qk + (size_t)(bS + q0 + row) * QK_ + h * 64 + sg * 8, Qs + i0 * 8);
  }
#pragma unroll
  for (int c = 0; c < 2; ++c) {
    const int i0 = c * 256 + wave * 64;
    const int i = i0 + lane;
    const int row = i >> 3, sg = (i & 7) ^ (row & 7);
    gl_lds16(qk + (size_t)(bS + row) * QK_ + 768 + h * 64 + sg * 8, Ks + i0 * 8);
    gl_lds16(vbase + (size_t)row * 1024 + sg * 8, Vts + i0 * 8);
  }
  __syncthreads();

  // qf[ks]: B-operand, col = l31 = q-row (wave's 32 rows), d = ks*16 + hi*8
  bf16x8 qf[4];
#pragma unroll
  for (int ks = 0; ks < 4; ++ks)
    qf[ks] = *(const bf16x8*)(Qs + (wave * 32 + l31) * 64 +
                              (((ks * 2 + hi) ^ l7) * 8));

  floatx16 oa[2];
  oa[0] = (floatx16)0.0f;
  oa[1] = (floatx16)0.0f;
  float lsum = 0.0f;

  for (int kv0 = 0; kv0 < S_; kv0 += 64) {
    if (kv0) {
      __syncthreads();   // WAR: all waves done with previous tile
#pragma unroll
      for (int c = 0; c < 2; ++c) {
        const int i0 = c * 256 + wave * 64;
        const int i = i0 + lane;
        const int row = i >> 3, sg = (i & 7) ^ (row & 7);
        gl_lds16(qk + (size_t)(bS + kv0 + row) * QK_ + 768 + h * 64 + sg * 8,
                 Ks + i0 * 8);
        gl_lds16(vbase + (size_t)row * 1024 + kv0 + sg * 8, Vts + i0 * 8);
      }
      __syncthreads();
    }

    // S^T = K Q^T : 2 kv-tiles x 4 d-steps, 8 MFMA(32x32x16)
    floatx16 sw0 = (floatx16)0.0f, sw1 = (floatx16)0.0f;
#pragma unroll
    for (int ks = 0; ks < 4; ++ks) {
      const bf16x8 kf0 = *(const bf16x8*)(Ks + (l31) * 64 + (((ks * 2 + hi) ^ l7) * 8));
      const bf16x8 kf1 = *(const bf16x8*)(Ks + (32 + l31) * 64 + (((ks * 2 + hi) ^ l7) * 8));
      sw0 = __builtin_amdgcn_mfma_f32_32x32x16_bf16(kf0, qf[ks], sw0, 0, 0, 0);
      sw1 = __builtin_amdgcn_mfma_f32_32x32x16_bf16(kf1, qf[ks], sw1, 0, 0, 0);
    }

    // softmax (in-register): p = exp2(s); build PV A-frag words
    uintx4 pw[4];   // [ks4]: kv quarters 0..3 (16 kv each)
#pragma unroll
    for (int tkv = 0; tkv < 2; ++tkv) {
      float p[16];
      float ps = 0.0f;
#pragma unroll
      for (int r = 0; r < 16; ++r) {
        p[r] = exp2f(tkv ? sw1[r] : sw0[r]);
        ps += p[r];
      }
      lsum += ps;
#pragma unroll
      for (int sub = 0; sub < 2; ++sub) {
        const int b = sub * 8;
        unsigned a0 = cvt_pk_bf16(p[b + 0], p[b + 1]);
        unsigned b0 = cvt_pk_bf16(p[b + 4], p[b + 5]);
        plane32_swap(a0, b0);    // a0 -> word0, b0 -> word2
        unsigned a1 = cvt_pk_bf16(p[b + 2], p[b + 3]);
        unsigned b1 = cvt_pk_bf16(p[b + 6], p[b + 7]);
        plane32_swap(a1, b1);    // a1 -> word1, b1 -> word3
        uintx4 w;
        w[0] = a0; w[1] = a1; w[2] = b0; w[3] = b1;
        pw[tkv * 2 + sub] = w;
      }
    }

    // O += P V : 2 d-tiles x 4 kv-steps, 8 MFMA(32x32x16)
#pragma unroll
    for (int dt = 0; dt < 2; ++dt)
#pragma unroll
      for (int ks4 = 0; ks4 < 4; ++ks4) {
        const bf16x8 vf = *(const bf16x8*)(Vts + (dt * 32 + l31) * 64 +
                                           (((ks4 * 2 + hi) ^ l7) * 8));
        const bf16x8 paf = __builtin_bit_cast(bf16x8, pw[ks4]);
        oa[dt] = __builtin_amdgcn_mfma_f32_32x32x16_bf16(paf, vf, oa[dt], 0, 0, 0);
      }
  }

  // full row-sum: the two half-waves partition each q-row's kv set
  lsum += __shfl_xor(lsum, 32, 64);
  if (lane < 32) Ls[wave * 32 + lane] = lsum;   // wave-private table

  // epilogue: normalize and store; O layout: col(l31)=d, rows by reg pattern
#pragma unroll
  for (int reg = 0; reg < 16; ++reg) {
    const int qrow = (reg & 3) + 8 * (reg >> 2) + 4 * hi;
    const float inv = 1.0f / Ls[wave * 32 + qrow];
    const int q = q0 + wave * 32 + qrow;
#pragma unroll
    for (int dt = 0; dt < 2; ++dt)
      o[(size_t)(bS + q) * D_ + h * 64 + dt * 32 + l31] = f2bf(oa[dt][reg] * inv);
  }
}

// ---------------------------------------------------------------------------
extern "C" void kernel_launch(void* const* d_in, const int* in_sizes, int n_in,
                              void* d_out, int out_size, void* d_ws, size_t ws_size,
                              hipStream_t stream) {
  const float* x      = (const float*)d_in[0];  // [8192, 768] f32
  const float* w_qkv  = (const float*)d_in[1];  // [768, 2304] f32
  const float* b_qkv  = (const float*)d_in[2];  // [2304] f32
  const float* w_proj = (const float*)d_in[3];  // [768, 768] f32
  const float* b_proj = (const float*)d_in[4];  // [768] f32
  float* out = (float*)d_out;                   // [8192, 768] f32

  ushort_t* xb = (ushort_t*)d_out;  // x as bf16, dead before proj GEMM writes

  // ws layout (bf16 units), 55.05 MB total (fault-free footprint)
  ushort_t* vtb    = (ushort_t*)d_ws;              // [96*64, 1024] 12.58 MB
  ushort_t* wqkvt  = vtb + (size_t)96 * 64 * 1024; // [2304, 768]    3.54 MB
  ushort_t* wprojt = wqkvt + (size_t)N3_ * D_;     // [768, 768]     1.18 MB
  ushort_t* qkb    = wprojt + (size_t)D_ * D_;     // [8192, 1536]  25.17 MB
  ushort_t* attnb  = qkb + (size_t)M_ * QK_;       // [8192, 768]   12.58 MB

  prep_kernel<<<6144 + 1728 + 576, 256, 0, stream>>>(x, xb, w_qkv, wqkvt,
                                                     w_proj, wprojt);
  // QKV: BM=256 x BN=128 -> 18 x 32 = 576 blocks (576 = 8*72)
  gemm_bm256<ushort_t, true><<<576, 512, 0, stream>>>(xb, wqkvt, b_qkv, qkb,
                                                      QK_, vtb, 18, 72);
  attn_kernel<<<dim3(768), 256, 0, stream>>>(qkb, vtb, attnb);
  gemm_bt_bias<float, false><<<dim3(D_ / 128, M_ / 128), 256, 0, stream>>>(
      attnb, wprojt, b_proj, out, D_, nullptr);
}